// Round 14
// baseline (2472.628 us; speedup 1.0000x reference)
//
#include <hip/hip_runtime.h>
#pragma clang fp contract(off)

#define BB 8
#define NN 8192
#define NP 2048
#define KNbr 16
#define FIN 64
#define NPOS (BB*NP*KNbr)   // 262144 positions
#define NCONS 248
#define AG __HIP_MEMORY_SCOPE_AGENT

typedef float f32x2 __attribute__((ext_vector_type(2)));
typedef unsigned long long u64;

// exact-order sum of squares: (x*x + y*y) + z*z, no FMA contraction
__device__ __forceinline__ float sq3(float x, float y, float z) {
  return __fadd_rn(__fadd_rn(__fmul_rn(x,x), __fmul_rn(y,y)), __fmul_rn(z,z));
}

// ---- wave64 reductions via DPP, VALU-pipe only ----
__device__ __forceinline__ int wave_imax(int x) {
  x = max(x, __builtin_amdgcn_update_dpp(0, x, 0x111, 0xf, 0xf, false));
  x = max(x, __builtin_amdgcn_update_dpp(0, x, 0x112, 0xf, 0xf, false));
  x = max(x, __builtin_amdgcn_update_dpp(0, x, 0x114, 0xf, 0xf, false));
  x = max(x, __builtin_amdgcn_update_dpp(0, x, 0x118, 0xf, 0xf, false));
  x = max(x, __builtin_amdgcn_update_dpp(0, x, 0x142, 0xa, 0xf, false));
  x = max(x, __builtin_amdgcn_update_dpp(0, x, 0x143, 0xc, 0xf, false));
  return __builtin_amdgcn_readlane(x, 63);
}
__device__ __forceinline__ unsigned wave_umin(unsigned x) {
  x = min(x, (unsigned)__builtin_amdgcn_update_dpp(-1, (int)x, 0x111, 0xf, 0xf, false));
  x = min(x, (unsigned)__builtin_amdgcn_update_dpp(-1, (int)x, 0x112, 0xf, 0xf, false));
  x = min(x, (unsigned)__builtin_amdgcn_update_dpp(-1, (int)x, 0x114, 0xf, 0xf, false));
  x = min(x, (unsigned)__builtin_amdgcn_update_dpp(-1, (int)x, 0x118, 0xf, 0xf, false));
  x = min(x, (unsigned)__builtin_amdgcn_update_dpp(-1, (int)x, 0x142, 0xa, 0xf, false));
  x = min(x, (unsigned)__builtin_amdgcn_update_dpp(-1, (int)x, 0x143, 0xc, 0xf, false));
  return (unsigned)__builtin_amdgcn_readlane((int)x, 63);
}

// ============ mega-front: fps producers (blocks 0-7) + prep/knn/y1/stats consumers (8-255) ============
// grid MUST be 256 blocks: LDS 128.3KB -> 1 block/CU -> all 256 co-resident -> polling is deadlock-free.
__global__ __launch_bounds__(256,1) void k_front2(const float* __restrict__ xyz,
                                                  const float* __restrict__ pts,
                                                  const float* __restrict__ W1,
                                                  const float* __restrict__ b1,
                                                  float4* __restrict__ xyzw,
                                                  float* __restrict__ qwf,
                                                  float* __restrict__ pre,
                                                  float* __restrict__ stats,
                                                  float* __restrict__ st2p,
                                                  int* __restrict__ prog,
                                                  int* __restrict__ pflag,
                                                  float* __restrict__ ybuf,
                                                  float* __restrict__ newxyz) {
  __shared__ float tx[NN], ty[NN], tz[NN];   // 96 KiB (fps centroid broadcast)
  __shared__ float4 res[NP];                 // 32 KiB (fps result stash, LDS-only in loop)
  __shared__ u64 skey[2][4];
  int blk = blockIdx.x, tid = threadIdx.x;
  int lane = tid & 63, wave = tid >> 6;

  if (blk >= 8) {
    // ---------- phase A: xyzw + pre1 (grid-stride over 65536 units) ----------
    for (int g = (blk-8)*256 + tid; g < BB*NN; g += NCONS*256) {
      int b = g >> 13, n = g & (NN-1);
      const float* p = xyz + (size_t)b*3*NN;
      float x = p[n], y = p[NN+n], z = p[2*NN+n];
      xyzw[g] = make_float4(x, y, z, sq3(x,y,z));
      const float* P = pts + (size_t)b*FIN*NN + n;
      float pv[64];
      #pragma unroll
      for (int i=0;i<64;++i) pv[i] = P[(size_t)i*NN];
      float4* outp = (float4*)(pre + (size_t)g*64);
      for (int og=0; og<16; ++og) {
        float acc[4];
        #pragma unroll
        for (int oo=0;oo<4;++oo) {
          int o = og*4+oo;
          float s = b1[o];
          #pragma unroll
          for (int i=0;i<64;++i) s = fmaf(W1[o*67+3+i], pv[i], s);
          acc[oo] = s;
        }
        outp[og] = make_float4(acc[0],acc[1],acc[2],acc[3]);
      }
    }
    if (blk == 8) stats[tid] = 0.f;                    // zero layer-1 stats
    if (blk >= 8 && blk < 24) st2p[(blk-8)*256 + tid] = 0.f;  // zero 32x128 layer-2 banks
    __syncthreads();                         // all waves' stores drained (vmcnt at barrier)
    if (tid == 0) {
      __threadfence();
      __hip_atomic_store(&pflag[blk-8], 1, __ATOMIC_RELEASE, AG);
    }
    // ---------- gate: wait for all 248 prep blocks (poison 0xAAAAAAAA != 1 -> safe) ----------
    bool ok = false;
    while (!ok) {
      int v = 1;
      for (int i = lane; i < NCONS; i += 64)
        v &= (__hip_atomic_load(&pflag[i], __ATOMIC_RELAXED, AG) == 1);
      ok = (bool)__all(v);
      if (!ok) __builtin_amdgcn_s_sleep(32);
    }
    __threadfence();

    // ---------- phase B: per-wave knn + y1 + stats, consuming fps output ----------
    int slot = (blk-8)*4 + wave;             // 0..991 ; b = slot&7 fixed per wave (L2 locality)
    float W1a = W1[lane*67+0], W1b = W1[lane*67+1], W1c = W1[lane*67+2];
    float sum = 0.f, ss = 0.f;
    for (int qi = slot; qi < BB*NP; qi += NCONS*4) {
      int t = qi >> 3, b = qi & 7;
      while (__hip_atomic_load(&prog[b*32], __ATOMIC_RELAXED, AG) <= t)  // signed: poison<0 blocks
        __builtin_amdgcn_s_sleep(16);
      const float* qp = qwf + ((size_t)(b*NP + t))*4;
      float qx  = __hip_atomic_load(qp+0, __ATOMIC_RELAXED, AG);
      float qy  = __hip_atomic_load(qp+1, __ATOMIC_RELAXED, AG);
      float qz  = __hip_atomic_load(qp+2, __ATOMIC_RELAXED, AG);
      float qw4 = __hip_atomic_load(qp+3, __ATOMIC_RELAXED, AG);
      // --- knn: lane-distributed sorted top-16 (exact lex (d,idx) order) ---
      const float4* base = xyzw + (size_t)b*NN;
      float ld = 3.0e38f; int li = 0x7fffffff;
      float taud = 3.0e38f; int taui = 0x7fffffff;
      for (int c = 0; c < 128; ++c) {
        int idx = c*64 + lane;
        float4 P = base[idx];
        float dot = __fadd_rn(__fadd_rn(__fmul_rn(P.x,qx), __fmul_rn(P.y,qy)), __fmul_rn(P.z,qz));
        float dd  = __fsub_rn(__fadd_rn(qw4, P.w), __fmul_rn(2.0f, dot));
        bool better = (dd < taud) || (dd == taud && idx < taui);
        u64 mask = __ballot(better);
        while (mask) {
          int src = __ffsll(mask) - 1;
          mask &= mask - 1;
          float bd = __shfl(dd, src, 64);
          int   bi = __shfl(idx, src, 64);
          bool before = (ld < bd) || (ld == bd && li < bi);
          float sd = __shfl_up(ld, 1, 64);
          int   si = __shfl_up(li, 1, 64);
          int   bp = __shfl_up((int)before, 1, 64);
          bool take_new = !before && (lane == 0 || bp);
          float nd = before ? ld : (take_new ? bd : sd);
          int   ni = before ? li : (take_new ? bi : si);
          if (lane < 16) { ld = nd; li = ni; }
          taud = __shfl(ld, 15, 64);
          taui = __shfl(li, 15, 64);
        }
      }
      // --- y1 (lane = channel) + stats accumulate ---
      const float* preb = pre + (size_t)b*NN*64;
      float* yb = ybuf + ((size_t)(b*NP + t))*16*64;
      for (int l=0;l<16;++l) {
        int n = __shfl(li, l, 64);
        float4 P = base[n];                          // wave-uniform broadcast
        float dx=__fsub_rn(P.x,qx), dy=__fsub_rn(P.y,qy), dz=__fsub_rn(P.z,qz);
        float v = fmaf(W1a, dx, fmaf(W1b, dy, fmaf(W1c, dz, preb[(size_t)n*64 + lane])));
        yb[l*64 + lane] = v;
        sum += v; ss = fmaf(v, v, ss);
      }
    }
    atomicAdd(&stats[lane], sum);
    atomicAdd(&stats[64+lane], ss);
    return;
  }

  // ---------- FPS (blocks 0-7): v6 LDS-only loop + chunked qw publish every 64 iters ----------
  int b = blk;
  const float* pxyz = xyz + (size_t)b*3*NN;
  f32x2 px[16], py[16], pz[16], d2[16];
  #pragma unroll
  for (int j=0;j<16;++j) {
    int i = j*512 + 2*tid;
    float2 xv = *(const float2*)(pxyz + i);
    float2 yv = *(const float2*)(pxyz + NN + i);
    float2 zv = *(const float2*)(pxyz + 2*NN + i);
    tx[i] = xv.x; tx[i+1] = xv.y;
    ty[i] = yv.x; ty[i+1] = yv.y;
    tz[i] = zv.x; tz[i+1] = zv.y;
    px[j] = f32x2{xv.x, xv.y};
    py[j] = f32x2{yv.x, yv.y};
    pz[j] = f32x2{zv.x, zv.y};
    d2[j] = f32x2{1e10f, 1e10f};
  }
  float cx = pxyz[0], cy = pxyz[NN], cz = pxyz[2*NN];
  if (tid==0) {
    res[0] = make_float4(cx, cy, cz, 0.f);
    __hip_atomic_store(qwf + (size_t)(b*NP)*4 + 0, cx, __ATOMIC_RELAXED, AG);
    __hip_atomic_store(qwf + (size_t)(b*NP)*4 + 1, cy, __ATOMIC_RELAXED, AG);
    __hip_atomic_store(qwf + (size_t)(b*NP)*4 + 2, cz, __ATOMIC_RELAXED, AG);
    __hip_atomic_store(qwf + (size_t)(b*NP)*4 + 3, sq3(cx,cy,cz), __ATOMIC_RELAXED, AG);
    __hip_atomic_store(&prog[b*32], 1, __ATOMIC_RELEASE, AG);
  }
  int w = tid>>6;
  __syncthreads();
  for (int t=1;t<NP;++t) {
    f32x2 cx2 = {cx,cx}, cy2 = {cy,cy}, cz2 = {cz,cz};
    #pragma unroll
    for (int j=0;j<16;++j) {
      f32x2 dx = px[j]-cx2, dy = py[j]-cy2, dz = pz[j]-cz2;
      f32x2 dd = (dx*dx + dy*dy) + dz*dz;     // contract(off): per-op rounding
#if __has_builtin(__builtin_elementwise_min)
      d2[j] = __builtin_elementwise_min(d2[j], dd);
#else
      d2[j].x = fminf(d2[j].x, dd.x);
      d2[j].y = fminf(d2[j].y, dd.y);
#endif
    }
    float tv[16]; int tk[16];
    #pragma unroll
    for (int j=0;j<16;++j) {
      bool r = d2[j].y > d2[j].x;
      tv[j] = r ? d2[j].y : d2[j].x;
      tk[j] = r ? 2*j+1 : 2*j;
    }
    #pragma unroll
    for (int j=0;j<8;++j) { bool r = tv[j+8] > tv[j]; if (r){tv[j]=tv[j+8]; tk[j]=tk[j+8];} }
    #pragma unroll
    for (int j=0;j<4;++j) { bool r = tv[j+4] > tv[j]; if (r){tv[j]=tv[j+4]; tk[j]=tk[j+4];} }
    #pragma unroll
    for (int j=0;j<2;++j) { bool r = tv[j+2] > tv[j]; if (r){tv[j]=tv[j+2]; tk[j]=tk[j+2];} }
    bool rr = tv[1] > tv[0];
    float lmax = rr ? tv[1] : tv[0];
    int   k    = rr ? tk[1] : tk[0];
    unsigned gidx = (unsigned)((k>>1)*512 + 2*tid + (k&1));
    int mb = wave_imax(__float_as_int(lmax));
    unsigned cand = (__float_as_int(lmax) == mb) ? gidx : 0xFFFFFFFFu;
    unsigned wwin = wave_umin(cand);
    int buf = t & 1;
    if ((tid & 63) == 0)
      skey[buf][w] = ((u64)(unsigned)mb << 32) | (u64)(0xFFFFFFFFu - wwin);
    __syncthreads();
    // chunked publish: entries [t-64, t) are final and (via the barrier) visible in LDS
    if ((t & 63) == 0) {
      int e = t - 64 + (tid >> 2), comp = tid & 3;
      float4 r = res[e];
      float v = (comp==0) ? r.x : (comp==1) ? r.y : (comp==2) ? r.z : sq3(r.x,r.y,r.z);
      __hip_atomic_store(qwf + ((size_t)(b*NP + e))*4 + comp, v, __ATOMIC_RELAXED, AG);
    } else if ((t & 63) == 1 && t > 64 && tid == 0) {
      __hip_atomic_store(&prog[b*32], t-1, __ATOMIC_RELEASE, AG);
    }
    u64 mk = skey[buf][0];
    if (skey[buf][1] > mk) mk = skey[buf][1];
    if (skey[buf][2] > mk) mk = skey[buf][2];
    if (skey[buf][3] > mk) mk = skey[buf][3];
    unsigned widx = 0xFFFFFFFFu - (unsigned)(mk & 0xFFFFFFFFull);
    cx = tx[widx]; cy = ty[widx]; cz = tz[widx];
    if (tid == (t & 255))
      res[t] = make_float4(cx, cy, cz, 0.f);
  }
  // end drain: rewrite all qw (coalesced) + newxyz, then final publish
  __syncthreads();
  float* outx = newxyz + (size_t)b*3*NP;
  #pragma unroll
  for (int s=0;s<8;++s) {
    int i = s*256 + tid;
    float4 r = res[i];
    *(float4*)(qwf + ((size_t)(b*NP + i))*4) = make_float4(r.x, r.y, r.z, sq3(r.x,r.y,r.z));
    outx[i] = r.x; outx[NP + i] = r.y; outx[2*NP + i] = r.z;
  }
  __syncthreads();                        // drains all waves' qw stores
  if (tid == 0) {
    __threadfence();
    __hip_atomic_store(&prog[b*32], NP, __ATOMIC_RELEASE, AG);
  }
}

// ---------------- conv2t: transposed compute (lane = position), x in VGPRs, W scalar ----------------
// 4096 blocks x 256 thr; tile = 64 pos x 64 ch; XOR-swizzled LDS, banked stats
__global__ __launch_bounds__(256) void k_conv2t(float* __restrict__ y,
                                                const float* __restrict__ W2,
                                                const float* __restrict__ b2,
                                                const float* __restrict__ st1,
                                                const float* __restrict__ g1,
                                                const float* __restrict__ be1,
                                                float* __restrict__ st2p) {
  __shared__ __align__(16) float4 xs[1024];    // swizzled activated input [pos][slot= j^(pos&15)]
  __shared__ float ys[4096];                   // transposed output [c][(pos^c)&63]
  __shared__ __align__(16) float sS[64], sT[64];
  __shared__ float r1[4][64], r2[4][64];
  int tid = threadIdx.x, lane = tid & 63, wave = tid >> 6;
  if (tid < 64) {
    float mean = st1[tid] * (1.0f/NPOS);
    float var  = st1[64+tid] * (1.0f/NPOS) - mean*mean;
    float istd = 1.0f / sqrtf(var + 1e-5f);
    float s = g1[tid]*istd;
    sS[tid] = s;
    sT[tid] = be1[tid] - mean*s;
  }
  __syncthreads();
  size_t tbase = (size_t)blockIdx.x * 1024;    // float4 index of tile start
  float4* Y4 = (float4*)y;
  // ---- coalesced load + act1 into swizzled LDS ----
  #pragma unroll
  for (int i=0;i<4;++i) {
    int idx = i*256 + tid;                     // pos = idx>>4, j = idx&15
    float4 v = Y4[tbase + idx];
    int c0 = (idx & 15)*4;
    float4 s4 = *(const float4*)(sS + c0);
    float4 t4 = *(const float4*)(sT + c0);
    v.x = fmaxf(0.f, fmaf(v.x, s4.x, t4.x));
    v.y = fmaxf(0.f, fmaf(v.y, s4.y, t4.y));
    v.z = fmaxf(0.f, fmaf(v.z, s4.z, t4.z));
    v.w = fmaxf(0.f, fmaf(v.w, s4.w, t4.w));
    int pos = idx >> 4, j = idx & 15;
    xs[pos*16 + (j ^ (pos & 15))] = v;
  }
  __syncthreads();
  // ---- x[64] of this lane's position into VGPRs (per-lane b128 reads, unswizzle) ----
  float4 x4[16];
  #pragma unroll
  for (int j=0;j<16;++j) x4[j] = xs[lane*16 + (j ^ (lane & 15))];
  // ---- wave handles 16 channels for all 64 positions; W via wave-uniform (scalar) loads ----
  int cb = wave*16;
  #pragma unroll 1
  for (int cc=0; cc<16; ++cc) {
    int c = cb + cc;
    const float4* Wr = (const float4*)(W2 + (size_t)c*64);
    float a0 = b2[c], a1 = 0.f, a2 = 0.f, a3 = 0.f;
    #pragma unroll
    for (int j=0;j<16;++j) {
      float4 wv = Wr[j];
      a0 = fmaf(x4[j].x, wv.x, a0);
      a1 = fmaf(x4[j].y, wv.y, a1);
      a2 = fmaf(x4[j].z, wv.z, a2);
      a3 = fmaf(x4[j].w, wv.w, a3);
    }
    ys[c*64 + ((lane ^ c) & 63)] = (a0+a1)+(a2+a3);
  }
  __syncthreads();
  // ---- coalesced global store from transposed tile ----
  #pragma unroll
  for (int i=0;i<4;++i) {
    int idx = i*256 + tid;
    int pos = idx >> 4, c0 = (idx & 15)*4;
    float4 v;
    v.x = ys[(c0+0)*64 + ((pos ^ (c0+0)) & 63)];
    v.y = ys[(c0+1)*64 + ((pos ^ (c0+1)) & 63)];
    v.z = ys[(c0+2)*64 + ((pos ^ (c0+2)) & 63)];
    v.w = ys[(c0+3)*64 + ((pos ^ (c0+3)) & 63)];
    Y4[tbase + idx] = v;
  }
  // ---- stats: thread (quarter=wave, channel=lane): sum its 16 positions (same grouping as R13) ----
  float s1 = 0.f, s2 = 0.f;
  #pragma unroll
  for (int p=0;p<16;++p) {
    int pos = wave*16 + p;
    float v = ys[lane*64 + ((pos ^ lane) & 63)];
    s1 += v; s2 = fmaf(v, v, s2);
  }
  r1[wave][lane] = s1; r2[wave][lane] = s2;
  __syncthreads();
  if (tid < 64) {
    float t1 = r1[0][tid]+r1[1][tid]+r1[2][tid]+r1[3][tid];
    float t2 = r2[0][tid]+r2[1][tid]+r2[2][tid]+r2[3][tid];
    float* bank = st2p + (blockIdx.x & 31)*128;
    atomicAdd(&bank[tid], t1);
    atomicAdd(&bank[64+tid], t2);
  }
}

// ---------------- c3t: transposed conv3 (lane = position) + DPP row-max over K ----------------
// 4096 blocks x 256 thr; tile = 64 pos = 4 queries; wave handles 32 of 128 out channels
__global__ __launch_bounds__(256) void k_c3t(const float* __restrict__ y,
                                             const float* __restrict__ W3,
                                             const float* __restrict__ b3,
                                             const float* __restrict__ st2p,
                                             const float* __restrict__ g2,
                                             const float* __restrict__ be2,
                                             float* __restrict__ feat) {
  __shared__ __align__(16) float4 xs[1024];    // swizzled activated input
  __shared__ __align__(16) float4 fs[128];     // [c] -> 4 query maxes
  __shared__ __align__(16) float sS[64], sT[64];
  int tid = threadIdx.x, lane = tid & 63, wave = tid >> 6;
  if (tid < 64) {
    float s1 = 0.f, s2 = 0.f;
    #pragma unroll
    for (int k=0;k<32;++k) {
      s1 += st2p[k*128 + tid];
      s2 += st2p[k*128 + 64 + tid];
    }
    float mean = s1 * (1.0f/NPOS);
    float var  = s2 * (1.0f/NPOS) - mean*mean;
    float istd = 1.0f / sqrtf(var + 1e-5f);
    float s = g2[tid]*istd;
    sS[tid] = s;
    sT[tid] = be2[tid] - mean*s;
  }
  __syncthreads();
  size_t tbase = (size_t)blockIdx.x * 1024;
  const float4* Y4 = (const float4*)y;
  #pragma unroll
  for (int i=0;i<4;++i) {
    int idx = i*256 + tid;
    float4 v = Y4[tbase + idx];
    int c0 = (idx & 15)*4;
    float4 s4 = *(const float4*)(sS + c0);
    float4 t4 = *(const float4*)(sT + c0);
    v.x = fmaxf(0.f, fmaf(v.x, s4.x, t4.x));
    v.y = fmaxf(0.f, fmaf(v.y, s4.y, t4.y));
    v.z = fmaxf(0.f, fmaf(v.z, s4.z, t4.z));
    v.w = fmaxf(0.f, fmaf(v.w, s4.w, t4.w));
    int pos = idx >> 4, j = idx & 15;
    xs[pos*16 + (j ^ (pos & 15))] = v;
  }
  __syncthreads();
  float4 x4[16];
  #pragma unroll
  for (int j=0;j<16;++j) x4[j] = xs[lane*16 + (j ^ (lane & 15))];
  int cb = wave*32;
  #pragma unroll 1
  for (int cc=0; cc<32; ++cc) {
    int c = cb + cc;
    const float4* Wr = (const float4*)(W3 + (size_t)c*64);
    float a0 = b3[c], a1 = 0.f, a2 = 0.f, a3 = 0.f;
    #pragma unroll
    for (int j=0;j<16;++j) {
      float4 wv = Wr[j];
      a0 = fmaf(x4[j].x, wv.x, a0);
      a1 = fmaf(x4[j].y, wv.y, a1);
      a2 = fmaf(x4[j].z, wv.z, a2);
      a3 = fmaf(x4[j].w, wv.w, a3);
    }
    float m = (a0+a1)+(a2+a3);
    // max over the 16 positions of each query (16-lane DPP rows, cumulative toward lane 15)
    m = fmaxf(m, __int_as_float(__builtin_amdgcn_update_dpp(__float_as_int(m), __float_as_int(m), 0x111, 0xf, 0xf, false)));
    m = fmaxf(m, __int_as_float(__builtin_amdgcn_update_dpp(__float_as_int(m), __float_as_int(m), 0x112, 0xf, 0xf, false)));
    m = fmaxf(m, __int_as_float(__builtin_amdgcn_update_dpp(__float_as_int(m), __float_as_int(m), 0x114, 0xf, 0xf, false)));
    m = fmaxf(m, __int_as_float(__builtin_amdgcn_update_dpp(__float_as_int(m), __float_as_int(m), 0x118, 0xf, 0xf, false)));
    if ((lane & 15) == 15) ((float*)fs)[c*4 + (lane >> 4)] = m;
  }
  __syncthreads();
  if (tid < 128) {
    float4 v = fs[tid];
    int gq0 = blockIdx.x*4;
    int b = gq0 >> 11, qq = gq0 & (NP-1);
    *(float4*)(feat + ((size_t)(b*128 + tid))*NP + qq) = v;
  }
}

extern "C" void kernel_launch(void* const* d_in, const int* in_sizes, int n_in,
                              void* d_out, int out_size, void* d_ws, size_t ws_size,
                              hipStream_t stream) {
  const float* xyz = (const float*)d_in[0];
  const float* pts = (const float*)d_in[1];
  const float* W1  = (const float*)d_in[2];
  const float* b1  = (const float*)d_in[3];
  const float* g1  = (const float*)d_in[4];
  const float* be1 = (const float*)d_in[5];
  const float* W2  = (const float*)d_in[6];
  const float* b2  = (const float*)d_in[7];
  const float* g2  = (const float*)d_in[8];
  const float* be2 = (const float*)d_in[9];
  const float* W3  = (const float*)d_in[10];
  const float* b3  = (const float*)d_in[11];
  float* out = (float*)d_out;
  float* ws  = (float*)d_ws;

  // workspace layout (float offsets)
  float4* xyzw  = (float4*)ws;                    //  65536 float4
  float*  qwf   = ws + 262144;                    //  65536 floats (qw as dwords, atomic-published)
  float*  pre   = ws + 1654784;                   //  4194304
  float*  ybuf  = ws + 5849088;                   //  16777216
  float*  stats = ws + 22626304;                  //  256 (layer-1)
  float*  st2p  = ws + 22626560;                  //  4096 = 32 banks x 128 (layer-2 partials)
  int*    prog  = (int*)(ws + 22630656);          //  8 batches x 32-int stride (1 line each)
  int*    pflag = (int*)(ws + 22630912);          //  248 (poison-safe: ==1 check)

  k_front2<<<256, 256, 0, stream>>>(xyz, pts, W1, b1, xyzw, qwf, pre, stats, st2p,
                                    prog, pflag, ybuf, out);
  k_conv2t<<<4096, 256, 0, stream>>>(ybuf, W2, b2, stats, g1, be1, st2p);
  k_c3t   <<<4096, 256, 0, stream>>>(ybuf, W3, b3, st2p, g2, be2, out + 49152);
}

// Round 15
// 2275.706 us; speedup vs baseline: 1.0865x; 1.0865x over previous
//
#include <hip/hip_runtime.h>
#pragma clang fp contract(off)

#define BB 8
#define NN 8192
#define NP 2048
#define KNbr 16
#define FIN 64
#define NPOS (BB*NP*KNbr)   // 262144 positions
#define NCONS 248
#define AG __HIP_MEMORY_SCOPE_AGENT

typedef float f32x2 __attribute__((ext_vector_type(2)));
typedef unsigned long long u64;

// exact-order sum of squares: (x*x + y*y) + z*z, no FMA contraction
__device__ __forceinline__ float sq3(float x, float y, float z) {
  return __fadd_rn(__fadd_rn(__fmul_rn(x,x), __fmul_rn(y,y)), __fmul_rn(z,z));
}

// ---- wave64 reductions via DPP, VALU-pipe only ----
__device__ __forceinline__ int wave_imax(int x) {
  x = max(x, __builtin_amdgcn_update_dpp(0, x, 0x111, 0xf, 0xf, false));
  x = max(x, __builtin_amdgcn_update_dpp(0, x, 0x112, 0xf, 0xf, false));
  x = max(x, __builtin_amdgcn_update_dpp(0, x, 0x114, 0xf, 0xf, false));
  x = max(x, __builtin_amdgcn_update_dpp(0, x, 0x118, 0xf, 0xf, false));
  x = max(x, __builtin_amdgcn_update_dpp(0, x, 0x142, 0xa, 0xf, false));
  x = max(x, __builtin_amdgcn_update_dpp(0, x, 0x143, 0xc, 0xf, false));
  return __builtin_amdgcn_readlane(x, 63);
}
__device__ __forceinline__ unsigned wave_umin(unsigned x) {
  x = min(x, (unsigned)__builtin_amdgcn_update_dpp(-1, (int)x, 0x111, 0xf, 0xf, false));
  x = min(x, (unsigned)__builtin_amdgcn_update_dpp(-1, (int)x, 0x112, 0xf, 0xf, false));
  x = min(x, (unsigned)__builtin_amdgcn_update_dpp(-1, (int)x, 0x114, 0xf, 0xf, false));
  x = min(x, (unsigned)__builtin_amdgcn_update_dpp(-1, (int)x, 0x118, 0xf, 0xf, false));
  x = min(x, (unsigned)__builtin_amdgcn_update_dpp(-1, (int)x, 0x142, 0xa, 0xf, false));
  x = min(x, (unsigned)__builtin_amdgcn_update_dpp(-1, (int)x, 0x143, 0xc, 0xf, false));
  return (unsigned)__builtin_amdgcn_readlane((int)x, 63);
}

// ============ mega-front: fps producers (blocks 0-7) + prep/knn/y1/stats consumers (8-255) ============
// grid MUST be 256 blocks: LDS 128.3KB -> 1 block/CU -> all 256 co-resident -> polling is deadlock-free.
__global__ __launch_bounds__(256,1) void k_front2(const float* __restrict__ xyz,
                                                  const float* __restrict__ pts,
                                                  const float* __restrict__ W1,
                                                  const float* __restrict__ b1,
                                                  float4* __restrict__ xyzw,
                                                  float* __restrict__ qwf,
                                                  float* __restrict__ pre,
                                                  float* __restrict__ stats,
                                                  float* __restrict__ st2p,
                                                  int* __restrict__ prog,
                                                  int* __restrict__ pflag,
                                                  float* __restrict__ ybuf,
                                                  float* __restrict__ newxyz) {
  __shared__ float tx[NN], ty[NN], tz[NN];   // 96 KiB (fps centroid broadcast)
  __shared__ float4 res[NP];                 // 32 KiB (fps result stash, LDS-only in loop)
  __shared__ u64 skey[2][4];
  int blk = blockIdx.x, tid = threadIdx.x;
  int lane = tid & 63, wave = tid >> 6;

  if (blk >= 8) {
    // ---------- phase A: xyzw + pre1 (grid-stride over 65536 units) ----------
    for (int g = (blk-8)*256 + tid; g < BB*NN; g += NCONS*256) {
      int b = g >> 13, n = g & (NN-1);
      const float* p = xyz + (size_t)b*3*NN;
      float x = p[n], y = p[NN+n], z = p[2*NN+n];
      xyzw[g] = make_float4(x, y, z, sq3(x,y,z));
      const float* P = pts + (size_t)b*FIN*NN + n;
      float pv[64];
      #pragma unroll
      for (int i=0;i<64;++i) pv[i] = P[(size_t)i*NN];
      float4* outp = (float4*)(pre + (size_t)g*64);
      for (int og=0; og<16; ++og) {
        float acc[4];
        #pragma unroll
        for (int oo=0;oo<4;++oo) {
          int o = og*4+oo;
          float s = b1[o];
          #pragma unroll
          for (int i=0;i<64;++i) s = fmaf(W1[o*67+3+i], pv[i], s);
          acc[oo] = s;
        }
        outp[og] = make_float4(acc[0],acc[1],acc[2],acc[3]);
      }
    }
    if (blk == 8) stats[tid] = 0.f;                    // zero layer-1 stats
    if (blk >= 8 && blk < 24) st2p[(blk-8)*256 + tid] = 0.f;  // zero 32x128 layer-2 banks
    __syncthreads();                         // all waves' stores drained (vmcnt at barrier)
    if (tid == 0) {
      __threadfence();
      __hip_atomic_store(&pflag[blk-8], 1, __ATOMIC_RELEASE, AG);
    }
    // ---------- gate: wait for all 248 prep blocks (poison 0xAAAAAAAA != 1 -> safe) ----------
    bool ok = false;
    while (!ok) {
      int v = 1;
      for (int i = lane; i < NCONS; i += 64)
        v &= (__hip_atomic_load(&pflag[i], __ATOMIC_RELAXED, AG) == 1);
      ok = (bool)__all(v);
      if (!ok) __builtin_amdgcn_s_sleep(32);
    }
    __threadfence();

    // ---------- phase B: per-wave knn + y1 + stats, consuming fps output ----------
    int slot = (blk-8)*4 + wave;             // 0..991 ; b = slot&7 fixed per wave (L2 locality)
    float W1a = W1[lane*67+0], W1b = W1[lane*67+1], W1c = W1[lane*67+2];
    float sum = 0.f, ss = 0.f;
    for (int qi = slot; qi < BB*NP; qi += NCONS*4) {
      int t = qi >> 3, b = qi & 7;
      while (__hip_atomic_load(&prog[b*32], __ATOMIC_RELAXED, AG) <= t)  // signed: poison<0 blocks
        __builtin_amdgcn_s_sleep(16);
      const float* qp = qwf + ((size_t)(b*NP + t))*4;
      float qx  = __hip_atomic_load(qp+0, __ATOMIC_RELAXED, AG);
      float qy  = __hip_atomic_load(qp+1, __ATOMIC_RELAXED, AG);
      float qz  = __hip_atomic_load(qp+2, __ATOMIC_RELAXED, AG);
      float qw4 = __hip_atomic_load(qp+3, __ATOMIC_RELAXED, AG);
      // --- knn: lane-distributed sorted top-16 (exact lex (d,idx) order) ---
      const float4* base = xyzw + (size_t)b*NN;
      float ld = 3.0e38f; int li = 0x7fffffff;
      float taud = 3.0e38f; int taui = 0x7fffffff;
      for (int c = 0; c < 128; ++c) {
        int idx = c*64 + lane;
        float4 P = base[idx];
        float dot = __fadd_rn(__fadd_rn(__fmul_rn(P.x,qx), __fmul_rn(P.y,qy)), __fmul_rn(P.z,qz));
        float dd  = __fsub_rn(__fadd_rn(qw4, P.w), __fmul_rn(2.0f, dot));
        bool better = (dd < taud) || (dd == taud && idx < taui);
        u64 mask = __ballot(better);
        while (mask) {
          int src = __ffsll(mask) - 1;
          mask &= mask - 1;
          float bd = __shfl(dd, src, 64);
          int   bi = __shfl(idx, src, 64);
          bool before = (ld < bd) || (ld == bd && li < bi);
          float sd = __shfl_up(ld, 1, 64);
          int   si = __shfl_up(li, 1, 64);
          int   bp = __shfl_up((int)before, 1, 64);
          bool take_new = !before && (lane == 0 || bp);
          float nd = before ? ld : (take_new ? bd : sd);
          int   ni = before ? li : (take_new ? bi : si);
          if (lane < 16) { ld = nd; li = ni; }
          taud = __shfl(ld, 15, 64);
          taui = __shfl(li, 15, 64);
        }
      }
      // --- y1 (lane = channel) + stats accumulate ---
      const float* preb = pre + (size_t)b*NN*64;
      float* yb = ybuf + ((size_t)(b*NP + t))*16*64;
      for (int l=0;l<16;++l) {
        int n = __shfl(li, l, 64);
        float4 P = base[n];                          // wave-uniform broadcast
        float dx=__fsub_rn(P.x,qx), dy=__fsub_rn(P.y,qy), dz=__fsub_rn(P.z,qz);
        float v = fmaf(W1a, dx, fmaf(W1b, dy, fmaf(W1c, dz, preb[(size_t)n*64 + lane])));
        yb[l*64 + lane] = v;
        sum += v; ss = fmaf(v, v, ss);
      }
    }
    atomicAdd(&stats[lane], sum);
    atomicAdd(&stats[64+lane], ss);
    return;
  }

  // ---------- FPS (blocks 0-7): v6 LDS-only loop + chunked qw publish every 64 iters ----------
  int b = blk;
  const float* pxyz = xyz + (size_t)b*3*NN;
  f32x2 px[16], py[16], pz[16], d2[16];
  #pragma unroll
  for (int j=0;j<16;++j) {
    int i = j*512 + 2*tid;
    float2 xv = *(const float2*)(pxyz + i);
    float2 yv = *(const float2*)(pxyz + NN + i);
    float2 zv = *(const float2*)(pxyz + 2*NN + i);
    tx[i] = xv.x; tx[i+1] = xv.y;
    ty[i] = yv.x; ty[i+1] = yv.y;
    tz[i] = zv.x; tz[i+1] = zv.y;
    px[j] = f32x2{xv.x, xv.y};
    py[j] = f32x2{yv.x, yv.y};
    pz[j] = f32x2{zv.x, zv.y};
    d2[j] = f32x2{1e10f, 1e10f};
  }
  float cx = pxyz[0], cy = pxyz[NN], cz = pxyz[2*NN];
  if (tid==0) {
    res[0] = make_float4(cx, cy, cz, 0.f);
    __hip_atomic_store(qwf + (size_t)(b*NP)*4 + 0, cx, __ATOMIC_RELAXED, AG);
    __hip_atomic_store(qwf + (size_t)(b*NP)*4 + 1, cy, __ATOMIC_RELAXED, AG);
    __hip_atomic_store(qwf + (size_t)(b*NP)*4 + 2, cz, __ATOMIC_RELAXED, AG);
    __hip_atomic_store(qwf + (size_t)(b*NP)*4 + 3, sq3(cx,cy,cz), __ATOMIC_RELAXED, AG);
    __hip_atomic_store(&prog[b*32], 1, __ATOMIC_RELEASE, AG);
  }
  int w = tid>>6;
  __syncthreads();
  for (int t=1;t<NP;++t) {
    f32x2 cx2 = {cx,cx}, cy2 = {cy,cy}, cz2 = {cz,cz};
    #pragma unroll
    for (int j=0;j<16;++j) {
      f32x2 dx = px[j]-cx2, dy = py[j]-cy2, dz = pz[j]-cz2;
      f32x2 dd = (dx*dx + dy*dy) + dz*dz;     // contract(off): per-op rounding
#if __has_builtin(__builtin_elementwise_min)
      d2[j] = __builtin_elementwise_min(d2[j], dd);
#else
      d2[j].x = fminf(d2[j].x, dd.x);
      d2[j].y = fminf(d2[j].y, dd.y);
#endif
    }
    float tv[16]; int tk[16];
    #pragma unroll
    for (int j=0;j<16;++j) {
      bool r = d2[j].y > d2[j].x;
      tv[j] = r ? d2[j].y : d2[j].x;
      tk[j] = r ? 2*j+1 : 2*j;
    }
    #pragma unroll
    for (int j=0;j<8;++j) { bool r = tv[j+8] > tv[j]; if (r){tv[j]=tv[j+8]; tk[j]=tk[j+8];} }
    #pragma unroll
    for (int j=0;j<4;++j) { bool r = tv[j+4] > tv[j]; if (r){tv[j]=tv[j+4]; tk[j]=tk[j+4];} }
    #pragma unroll
    for (int j=0;j<2;++j) { bool r = tv[j+2] > tv[j]; if (r){tv[j]=tv[j+2]; tk[j]=tk[j+2];} }
    bool rr = tv[1] > tv[0];
    float lmax = rr ? tv[1] : tv[0];
    int   k    = rr ? tk[1] : tk[0];
    unsigned gidx = (unsigned)((k>>1)*512 + 2*tid + (k&1));
    int mb = wave_imax(__float_as_int(lmax));
    unsigned cand = (__float_as_int(lmax) == mb) ? gidx : 0xFFFFFFFFu;
    unsigned wwin = wave_umin(cand);
    int buf = t & 1;
    if ((tid & 63) == 0)
      skey[buf][w] = ((u64)(unsigned)mb << 32) | (u64)(0xFFFFFFFFu - wwin);
    __syncthreads();
    // chunked publish: entries [t-64, t) are final and (via the barrier) visible in LDS
    if ((t & 63) == 0) {
      int e = t - 64 + (tid >> 2), comp = tid & 3;
      float4 r = res[e];
      float v = (comp==0) ? r.x : (comp==1) ? r.y : (comp==2) ? r.z : sq3(r.x,r.y,r.z);
      __hip_atomic_store(qwf + ((size_t)(b*NP + e))*4 + comp, v, __ATOMIC_RELAXED, AG);
    } else if ((t & 63) == 1 && t > 64 && tid == 0) {
      // previous chunk's stores were drained by this iteration's __syncthreads (vmcnt(0) per wave)
      __hip_atomic_store(&prog[b*32], t-1, __ATOMIC_RELEASE, AG);
    }
    u64 mk = skey[buf][0];
    if (skey[buf][1] > mk) mk = skey[buf][1];
    if (skey[buf][2] > mk) mk = skey[buf][2];
    if (skey[buf][3] > mk) mk = skey[buf][3];
    unsigned widx = 0xFFFFFFFFu - (unsigned)(mk & 0xFFFFFFFFull);
    cx = tx[widx]; cy = ty[widx]; cz = tz[widx];
    if (tid == (t & 255))
      res[t] = make_float4(cx, cy, cz, 0.f);
  }
  // end drain: rewrite all qw (coalesced) + newxyz, then final publish
  __syncthreads();
  float* outx = newxyz + (size_t)b*3*NP;
  #pragma unroll
  for (int s=0;s<8;++s) {
    int i = s*256 + tid;
    float4 r = res[i];
    *(float4*)(qwf + ((size_t)(b*NP + i))*4) = make_float4(r.x, r.y, r.z, sq3(r.x,r.y,r.z));
    outx[i] = r.x; outx[NP + i] = r.y; outx[2*NP + i] = r.z;
  }
  __syncthreads();                        // drains all waves' qw stores
  if (tid == 0) {
    __threadfence();
    __hip_atomic_store(&prog[b*32], NP, __ATOMIC_RELEASE, AG);
  }
}

// ---------------- dot of 64 with 4 partial accumulators ----------------
__device__ __forceinline__ float dot64(const float4* x, const float* W, float init) {
  float a0 = init, a1 = 0.f, a2 = 0.f, a3 = 0.f;
  #pragma unroll
  for (int j=0;j<16;++j) {
    float4 v = x[j];
    a0 = fmaf(v.x, W[4*j],   a0);
    a1 = fmaf(v.y, W[4*j+1], a1);
    a2 = fmaf(v.z, W[4*j+2], a2);
    a3 = fmaf(v.w, W[4*j+3], a3);
  }
  return (a0+a1)+(a2+a3);
}

// ---------------- conv2f: act1-on-load (LDS tile) + conv2 + banked stats2; in-place ----------------
// 4096 blocks x 256 thr; tile = 64 positions x 64 ch = 16KB LDS; stats to bank (blk&31)
__global__ __launch_bounds__(256) void k_conv2f(float* __restrict__ y,
                                                const float* __restrict__ W2,
                                                const float* __restrict__ b2,
                                                const float* __restrict__ st1,
                                                const float* __restrict__ g1,
                                                const float* __restrict__ be1,
                                                float* __restrict__ st2p) {
  __shared__ __align__(16) float4 xs[1024];    // 16KB activated tile (pos-major, 16 f4/pos)
  __shared__ __align__(16) float sS[64], sT[64];
  __shared__ float r1[4][64], r2[4][64];
  int tid = threadIdx.x, lane = tid & 63, wave = tid >> 6;
  if (tid < 64) {
    float mean = st1[tid] * (1.0f/NPOS);
    float var  = st1[64+tid] * (1.0f/NPOS) - mean*mean;
    float istd = 1.0f / sqrtf(var + 1e-5f);
    float s = g1[tid]*istd;
    sS[tid] = s;
    sT[tid] = be1[tid] - mean*s;
  }
  // W row for this lane (out channel)
  float W[64];
  #pragma unroll
  for (int j=0;j<16;++j) {
    float4 t = *(const float4*)(W2 + (size_t)lane*64 + j*4);
    W[4*j]=t.x; W[4*j+1]=t.y; W[4*j+2]=t.z; W[4*j+3]=t.w;
  }
  float bb = b2[lane];
  __syncthreads();
  size_t tbase = (size_t)blockIdx.x * 1024;    // float4 index of tile start
  float4* Y4 = (float4*)y;
  // ---- coalesced load + act1 into LDS ----
  #pragma unroll
  for (int i=0;i<4;++i) {
    int idx = i*256 + tid;                     // 0..1023 ; c4 = idx&15
    float4 v = Y4[tbase + idx];
    int c0 = (idx & 15)*4;
    float4 s4 = *(const float4*)(sS + c0);
    float4 t4 = *(const float4*)(sT + c0);
    v.x = fmaxf(0.f, fmaf(v.x, s4.x, t4.x));
    v.y = fmaxf(0.f, fmaf(v.y, s4.y, t4.y));
    v.z = fmaxf(0.f, fmaf(v.z, s4.z, t4.z));
    v.w = fmaxf(0.f, fmaf(v.w, s4.w, t4.w));
    xs[idx] = v;
  }
  __syncthreads();
  // ---- compute: wave handles 16 positions; lane = out channel ----
  float sum = 0.f, ss = 0.f;
  size_t pos0 = (size_t)blockIdx.x*64 + wave*16;
  #pragma unroll 1
  for (int p=0;p<16;++p) {
    float acc = dot64(&xs[(wave*16+p)*16], W, bb);
    y[(pos0+p)*64 + lane] = acc;
    sum += acc; ss = fmaf(acc, acc, ss);
  }
  r1[wave][lane] = sum; r2[wave][lane] = ss;
  __syncthreads();
  if (tid < 64) {
    float t1 = r1[0][tid]+r1[1][tid]+r1[2][tid]+r1[3][tid];
    float t2 = r2[0][tid]+r2[1][tid]+r2[2][tid]+r2[3][tid];
    float* bank = st2p + (blockIdx.x & 31)*128;   // 32 disjoint banks: 32x less contention
    atomicAdd(&bank[tid], t1);
    atomicAdd(&bank[64+tid], t2);
  }
}

// ---------------- c3f: act2-on-load (LDS tile) + conv3 + max over K ----------------
// 4096 blocks x 256 thr; tile = 64 positions = 4 queries; bn2 from 32 stat banks
__global__ __launch_bounds__(256) void k_c3f(const float* __restrict__ y,
                                             const float* __restrict__ W3,
                                             const float* __restrict__ b3,
                                             const float* __restrict__ st2p,
                                             const float* __restrict__ g2,
                                             const float* __restrict__ be2,
                                             float* __restrict__ feat) {
  __shared__ __align__(16) float4 xs[1024];    // 16KB activated tile
  __shared__ __align__(16) float sS[64], sT[64];
  int tid = threadIdx.x, lane = tid & 63, wave = tid >> 6;
  int h = wave & 1, qpair = wave >> 1;         // h: channel half, qpair: queries {2q,2q+1}
  if (tid < 64) {
    float s1 = 0.f, s2 = 0.f;
    #pragma unroll
    for (int k=0;k<32;++k) {
      s1 += st2p[k*128 + tid];
      s2 += st2p[k*128 + 64 + tid];
    }
    float mean = s1 * (1.0f/NPOS);
    float var  = s2 * (1.0f/NPOS) - mean*mean;
    float istd = 1.0f / sqrtf(var + 1e-5f);
    float s = g2[tid]*istd;
    sS[tid] = s;
    sT[tid] = be2[tid] - mean*s;
  }
  int O = h*64 + lane;
  float W[64];
  #pragma unroll
  for (int j=0;j<16;++j) {
    float4 t = *(const float4*)(W3 + (size_t)O*64 + j*4);
    W[4*j]=t.x; W[4*j+1]=t.y; W[4*j+2]=t.z; W[4*j+3]=t.w;
  }
  float bb = b3[O];
  __syncthreads();
  size_t tbase = (size_t)blockIdx.x * 1024;
  const float4* Y4 = (const float4*)y;
  #pragma unroll
  for (int i=0;i<4;++i) {
    int idx = i*256 + tid;
    float4 v = Y4[tbase + idx];
    int c0 = (idx & 15)*4;
    float4 s4 = *(const float4*)(sS + c0);
    float4 t4 = *(const float4*)(sT + c0);
    v.x = fmaxf(0.f, fmaf(v.x, s4.x, t4.x));
    v.y = fmaxf(0.f, fmaf(v.y, s4.y, t4.y));
    v.z = fmaxf(0.f, fmaf(v.z, s4.z, t4.z));
    v.w = fmaxf(0.f, fmaf(v.w, s4.w, t4.w));
    xs[idx] = v;
  }
  __syncthreads();
  // wave computes 2 queries (32 positions) for its channel half
  float mq[2];
  #pragma unroll 1
  for (int q=0;q<2;++q) {
    float m = -3.0e38f;
    #pragma unroll 1
    for (int k=0;k<16;++k) {
      int p = (qpair*2 + q)*16 + k;
      m = fmaxf(m, dot64(&xs[p*16], W, bb));
    }
    mq[q] = m;
  }
  int gq0 = blockIdx.x*4 + qpair*2;            // global query of mq[0]
  int b = gq0 >> 11, qq = gq0 & (NP-1);
  float* fp = feat + ((size_t)(b*128 + O))*NP + qq;
  fp[0] = mq[0];
  fp[1] = mq[1];
}

extern "C" void kernel_launch(void* const* d_in, const int* in_sizes, int n_in,
                              void* d_out, int out_size, void* d_ws, size_t ws_size,
                              hipStream_t stream) {
  const float* xyz = (const float*)d_in[0];
  const float* pts = (const float*)d_in[1];
  const float* W1  = (const float*)d_in[2];
  const float* b1  = (const float*)d_in[3];
  const float* g1  = (const float*)d_in[4];
  const float* be1 = (const float*)d_in[5];
  const float* W2  = (const float*)d_in[6];
  const float* b2  = (const float*)d_in[7];
  const float* g2  = (const float*)d_in[8];
  const float* be2 = (const float*)d_in[9];
  const float* W3  = (const float*)d_in[10];
  const float* b3  = (const float*)d_in[11];
  float* out = (float*)d_out;
  float* ws  = (float*)d_ws;

  // workspace layout (float offsets)
  float4* xyzw  = (float4*)ws;                    //  65536 float4
  float*  qwf   = ws + 262144;                    //  65536 floats (qw as dwords, atomic-published)
  float*  pre   = ws + 1654784;                   //  4194304
  float*  ybuf  = ws + 5849088;                   //  16777216
  float*  stats = ws + 22626304;                  //  256 (layer-1)
  float*  st2p  = ws + 22626560;                  //  4096 = 32 banks x 128 (layer-2 partials)
  int*    prog  = (int*)(ws + 22630656);          //  8 batches x 32-int stride (1 line each)
  int*    pflag = (int*)(ws + 22630912);          //  248 (poison-safe: ==1 check)

  k_front2<<<256, 256, 0, stream>>>(xyz, pts, W1, b1, xyzw, qwf, pre, stats, st2p,
                                    prog, pflag, ybuf, out);
  k_conv2f<<<4096, 256, 0, stream>>>(ybuf, W2, b2, stats, g1, be1, st2p);
  k_c3f   <<<4096, 256, 0, stream>>>(ybuf, W3, b3, st2p, g2, be2, out + 49152);
}